// Round 1
// baseline (2241.389 us; speedup 1.0000x reference)
//
#include <hip/hip_runtime.h>
#include <hip/hip_bf16.h>

#define N_NODES 100000
#define N_EDGES 300000
#define CH 256
#define EPS 1e-5f

typedef __hip_bfloat16 bf16;

__device__ __forceinline__ void store_val(float* p, float v) { *p = v; }
__device__ __forceinline__ void store_val(bf16* p, float v) { *p = __float2bfloat16(v); }
__device__ __forceinline__ float load_val(const float* p) { return *p; }
__device__ __forceinline__ float load_val(const bf16* p) { return __bfloat162float(*p); }

// ---------------- degree / dinv ----------------
__global__ void k_init_deg(float* deg) {
    int i = blockIdx.x * 256 + threadIdx.x;
    if (i < N_NODES) deg[i] = 1.0f;  // self loop contributes 1
}
__global__ void k_deg_edges(const int* __restrict__ dst, float* deg) {
    int e = blockIdx.x * 256 + threadIdx.x;
    if (e < N_EDGES) atomicAdd(&deg[dst[e]], 1.0f);
}
__global__ void k_finalize_dinv(float* deg) {
    int i = blockIdx.x * 256 + threadIdx.x;
    if (i < N_NODES) deg[i] = rsqrtf(deg[i]);  // deg >= 1 always
}

// ---------------- GEMM: C[M x 256] = A[M x 256] @ B[256 x 256] ----------------
// 64x64 tile, 256 threads, 4x4 micro-tile, K-step 16.
template <typename OutT>
__global__ void k_gemm(const float* __restrict__ A, const float* __restrict__ B,
                       OutT* __restrict__ C, int M) {
    __shared__ float As[16][64];
    __shared__ float Bs[16][64];
    const int tid = threadIdx.x;
    const int tx = tid & 15, ty = tid >> 4;
    const int row0 = blockIdx.y * 64;
    const int col0 = blockIdx.x * 64;

    const int lm = tid >> 2;          // 0..63 (A row within tile)
    const int lk = (tid & 3) * 4;     // 0,4,8,12 (A k quad)
    const int bk = tid >> 4;          // 0..15 (B k)
    const int bn = (tid & 15) * 4;    // 0..60 (B col quad)

    float acc[4][4] = {};
    for (int k0 = 0; k0 < 256; k0 += 16) {
        float4 av = make_float4(0.f, 0.f, 0.f, 0.f);
        int ar = row0 + lm;
        if (ar < M) av = *(const float4*)(A + (size_t)ar * 256 + k0 + lk);
        As[lk + 0][lm] = av.x; As[lk + 1][lm] = av.y;
        As[lk + 2][lm] = av.z; As[lk + 3][lm] = av.w;
        *(float4*)(&Bs[bk][bn]) = *(const float4*)(B + (size_t)(k0 + bk) * 256 + col0 + bn);
        __syncthreads();
#pragma unroll
        for (int k = 0; k < 16; ++k) {
            float a0 = As[k][ty * 4 + 0], a1 = As[k][ty * 4 + 1];
            float a2 = As[k][ty * 4 + 2], a3 = As[k][ty * 4 + 3];
            float b0 = Bs[k][tx * 4 + 0], b1 = Bs[k][tx * 4 + 1];
            float b2 = Bs[k][tx * 4 + 2], b3 = Bs[k][tx * 4 + 3];
            acc[0][0] += a0 * b0; acc[0][1] += a0 * b1; acc[0][2] += a0 * b2; acc[0][3] += a0 * b3;
            acc[1][0] += a1 * b0; acc[1][1] += a1 * b1; acc[1][2] += a1 * b2; acc[1][3] += a1 * b3;
            acc[2][0] += a2 * b0; acc[2][1] += a2 * b1; acc[2][2] += a2 * b2; acc[2][3] += a2 * b3;
            acc[3][0] += a3 * b0; acc[3][1] += a3 * b1; acc[3][2] += a3 * b2; acc[3][3] += a3 * b3;
        }
        __syncthreads();
    }
#pragma unroll
    for (int i = 0; i < 4; ++i) {
        int r = row0 + ty * 4 + i;
        if (r < M) {
#pragma unroll
            for (int j = 0; j < 4; ++j)
                store_val(C + (size_t)r * 256 + col0 + tx * 4 + j, acc[i][j]);
        }
    }
}

// ---------------- aggregation ----------------
__global__ void k_agg_self(const float* __restrict__ xw, const float* __restrict__ dinv,
                           const float* __restrict__ bias, float* __restrict__ out) {
    int i = blockIdx.x * 256 + threadIdx.x;
    if (i < N_NODES * CH) {
        int node = i >> 8, c = i & 255;
        float dv = dinv[node];
        out[i] = dv * dv * xw[i] + bias[c];
    }
}
__global__ void k_agg_edges(const float* __restrict__ xw, const float* __restrict__ dinv,
                            const int* __restrict__ src, const int* __restrict__ dst,
                            float* __restrict__ out) {
    int e = blockIdx.x;
    int c = threadIdx.x;
    int s = src[e], d = dst[e];
    float w = dinv[s] * dinv[d];
    atomicAdd(&out[(size_t)d * CH + c], w * xw[(size_t)s * CH + c]);
}

// ---------------- batch norm ----------------
__global__ void k_bn_zero(float* bnsum, float* bnsumsq) {
    int c = threadIdx.x;
    bnsum[c] = 0.f; bnsumsq[c] = 0.f;
}
__global__ void k_bn_stats(const float* __restrict__ x, float* bnsum, float* bnsumsq) {
    int c = threadIdx.x;
    int r0 = blockIdx.x * 256;
    int rend = min(r0 + 256, N_NODES);
    float s = 0.f, q = 0.f;
    for (int r = r0; r < rend; ++r) {
        float v = x[(size_t)r * CH + c];
        s += v; q += v * v;
    }
    atomicAdd(&bnsum[c], s);
    atomicAdd(&bnsumsq[c], q);
}
__global__ void k_bn_finalize(const float* bnsum, const float* bnsumsq,
                              const float* __restrict__ g, const float* __restrict__ be,
                              float* scale, float* shift) {
    int c = threadIdx.x;
    float mu = bnsum[c] * (1.0f / N_NODES);
    float var = bnsumsq[c] * (1.0f / N_NODES) - mu * mu;
    float sc = g[c] * rsqrtf(var + EPS);
    scale[c] = sc;
    shift[c] = be[c] - mu * sc;
}
__global__ void k_bn_apply_relu(float* __restrict__ x, const float* __restrict__ scale,
                                const float* __restrict__ shift) {
    int i = blockIdx.x * 256 + threadIdx.x;
    if (i < N_NODES * CH) {
        int c = i & 255;
        float v = x[i] * scale[c] + shift[c];
        x[i] = v > 0.f ? v : 0.f;
    }
}

// ---------------- edge scoring ----------------
// pos = sigmoid( relu(u[src] + v[dst] + fc1_b) . fc2_w + fc2_b )
// neg = sigmoid( relu(u[src] + v[neg] + fc1_b) . fc2_w + fc2_b )
template <typename T>
__global__ void k_edge_score(const T* __restrict__ u, const T* __restrict__ v,
                             const int* __restrict__ src, const int* __restrict__ dst,
                             const int* __restrict__ neg, const float* __restrict__ fc1_b,
                             const float* __restrict__ fc2_w, const float* __restrict__ fc2_b,
                             float* __restrict__ out) {
    int wave = threadIdx.x >> 6, lane = threadIdx.x & 63;
    int e = blockIdx.x * 4 + wave;
    if (e >= N_EDGES) return;
    int s = src[e], d = dst[e], g = neg[e];
    const T* us = u + (size_t)s * CH;
    const T* vd = v + (size_t)d * CH;
    const T* vg = v + (size_t)g * CH;
    float accp = 0.f, accn = 0.f;
#pragma unroll
    for (int j = 0; j < 4; ++j) {
        int c = lane + j * 64;
        float t = load_val(us + c) + fc1_b[c];
        float hp = t + load_val(vd + c); hp = hp > 0.f ? hp : 0.f;
        float hn = t + load_val(vg + c); hn = hn > 0.f ? hn : 0.f;
        float w = fc2_w[c];
        accp += hp * w;
        accn += hn * w;
    }
#pragma unroll
    for (int off = 32; off > 0; off >>= 1) {
        accp += __shfl_down(accp, off, 64);
        accn += __shfl_down(accn, off, 64);
    }
    if (lane == 0) {
        float bb = fc2_b[0];
        out[e] = 1.0f / (1.0f + expf(-(accp + bb)));
        out[N_EDGES + e] = 1.0f / (1.0f + expf(-(accn + bb)));
    }
}

extern "C" void kernel_launch(void* const* d_in, const int* in_sizes, int n_in,
                              void* d_out, int out_size, void* d_ws, size_t ws_size,
                              hipStream_t stream) {
    const float* node_feat = (const float*)d_in[0];
    const int* src = (const int*)d_in[1];
    const int* dst = (const int*)d_in[2];
    const int* neg = (const int*)d_in[3];
    const float* W1 = (const float*)d_in[4];  const float* b1 = (const float*)d_in[5];
    const float* W2 = (const float*)d_in[6];  const float* b2 = (const float*)d_in[7];
    const float* W3 = (const float*)d_in[8];  const float* b3 = (const float*)d_in[9];
    const float* g1 = (const float*)d_in[10]; const float* be1 = (const float*)d_in[11];
    const float* g2 = (const float*)d_in[12]; const float* be2 = (const float*)d_in[13];
    const float* fc1_w = (const float*)d_in[14]; const float* fc1_b = (const float*)d_in[15];
    const float* fc2_w = (const float*)d_in[16]; const float* fc2_b = (const float*)d_in[17];
    float* out = (float*)d_out;

    const size_t NF = (size_t)N_NODES * CH;  // 25,600,000
    float* bufA = (float*)d_ws;
    float* bufB = bufA + NF;
    float* dinv = bufB + NF;
    float* bnsum = dinv + N_NODES;
    float* bnsumsq = bnsum + CH;
    float* scale = bnsumsq + CH;
    float* shift = scale + CH;
    float* bufC = shift + CH;  // fp32 u,v live here if ws permits

    // fp32 u/v needs bufC of 2*NF floats on top of everything before it.
    size_t need_f32 = ((size_t)(bufC + 2 * NF) - (size_t)d_ws);
    bool uv_f32 = ws_size >= need_f32;

    dim3 gemmGrid(4, (N_NODES + 63) / 64);
    int elemBlocks = (N_NODES * CH + 255) / 256;  // 100000
    int nodeBlocks = (N_NODES + 255) / 256;       // 391
    int edgeBlocks = (N_EDGES + 255) / 256;

    // degree -> dinv
    k_init_deg<<<nodeBlocks, 256, 0, stream>>>(dinv);
    k_deg_edges<<<edgeBlocks, 256, 0, stream>>>(dst, dinv);
    k_finalize_dinv<<<nodeBlocks, 256, 0, stream>>>(dinv);

    // ---- layer 1 ----
    k_gemm<float><<<gemmGrid, 256, 0, stream>>>(node_feat, W1, bufA, N_NODES);
    k_agg_self<<<elemBlocks, 256, 0, stream>>>(bufA, dinv, b1, bufB);
    k_agg_edges<<<N_EDGES, 256, 0, stream>>>(bufA, dinv, src, dst, bufB);
    k_bn_zero<<<1, 256, 0, stream>>>(bnsum, bnsumsq);
    k_bn_stats<<<nodeBlocks, 256, 0, stream>>>(bufB, bnsum, bnsumsq);
    k_bn_finalize<<<1, 256, 0, stream>>>(bnsum, bnsumsq, g1, be1, scale, shift);
    k_bn_apply_relu<<<elemBlocks, 256, 0, stream>>>(bufB, scale, shift);

    // ---- layer 2 ----
    k_gemm<float><<<gemmGrid, 256, 0, stream>>>(bufB, W2, bufA, N_NODES);
    k_agg_self<<<elemBlocks, 256, 0, stream>>>(bufA, dinv, b2, bufB);
    k_agg_edges<<<N_EDGES, 256, 0, stream>>>(bufA, dinv, src, dst, bufB);
    k_bn_zero<<<1, 256, 0, stream>>>(bnsum, bnsumsq);
    k_bn_stats<<<nodeBlocks, 256, 0, stream>>>(bufB, bnsum, bnsumsq);
    k_bn_finalize<<<1, 256, 0, stream>>>(bnsum, bnsumsq, g2, be2, scale, shift);
    k_bn_apply_relu<<<elemBlocks, 256, 0, stream>>>(bufB, scale, shift);

    // ---- layer 3 (no BN/relu): z in bufB ----
    k_gemm<float><<<gemmGrid, 256, 0, stream>>>(bufB, W3, bufA, N_NODES);
    k_agg_self<<<elemBlocks, 256, 0, stream>>>(bufA, dinv, b3, bufB);
    k_agg_edges<<<N_EDGES, 256, 0, stream>>>(bufA, dinv, src, dst, bufB);

    // ---- link predictor: u = z @ fc1_w[:256], v = z @ fc1_w[256:] ----
    int scoreBlocks = (N_EDGES + 3) / 4;
    if (uv_f32) {
        float* u = bufC;
        float* v = bufC + NF;
        k_gemm<float><<<gemmGrid, 256, 0, stream>>>(bufB, fc1_w, u, N_NODES);
        k_gemm<float><<<gemmGrid, 256, 0, stream>>>(bufB, fc1_w + CH * CH, v, N_NODES);
        k_edge_score<float><<<scoreBlocks, 256, 0, stream>>>(u, v, src, dst, neg,
                                                             fc1_b, fc2_w, fc2_b, out);
    } else {
        // bf16 fallback: u,v overwrite bufA (xw3 is dead)
        bf16* u = (bf16*)bufA;
        bf16* v = u + NF;
        k_gemm<bf16><<<gemmGrid, 256, 0, stream>>>(bufB, fc1_w, u, N_NODES);
        k_gemm<bf16><<<gemmGrid, 256, 0, stream>>>(bufB, fc1_w + CH * CH, v, N_NODES);
        k_edge_score<bf16><<<scoreBlocks, 256, 0, stream>>>(u, v, src, dst, neg,
                                                            fc1_b, fc2_w, fc2_b, out);
    }
}

// Round 2
// 1531.487 us; speedup vs baseline: 1.4635x; 1.4635x over previous
//
#include <hip/hip_runtime.h>
#include <hip/hip_bf16.h>

#define N_NODES 100000
#define N_EDGES 300000
#define CH 256
#define EPS 1e-5f

typedef __hip_bfloat16 bf16;

__device__ __forceinline__ void store_val(float* p, float v) { *p = v; }
__device__ __forceinline__ void store_val(bf16* p, float v) { *p = __float2bfloat16(v); }
__device__ __forceinline__ float load_val(const float* p) { return *p; }
__device__ __forceinline__ float load_val(const bf16* p) { return __bfloat162float(*p); }

// ================= CSR build =================
__global__ void k_zero_int(int* __restrict__ p, int n) {
    int i = blockIdx.x * 256 + threadIdx.x;
    if (i < n) p[i] = 0;
}
__global__ void k_count_deg(const int* __restrict__ dst, int* __restrict__ deg) {
    int e = blockIdx.x * 256 + threadIdx.x;
    if (e < N_EDGES) atomicAdd(&deg[dst[e]], 1);
}
__global__ void k_dinv_from_deg(const int* __restrict__ deg, float* __restrict__ dinv) {
    int i = blockIdx.x * 256 + threadIdx.x;
    if (i < N_NODES) dinv[i] = rsqrtf((float)(deg[i] + 1));  // +1 self loop
}
// per-256-chunk sums of deg
__global__ void k_block_sums(const int* __restrict__ deg, int* __restrict__ bsum) {
    __shared__ int s[256];
    int t = threadIdx.x;
    int i = blockIdx.x * 256 + t;
    s[t] = (i < N_NODES) ? deg[i] : 0;
    __syncthreads();
    for (int off = 128; off > 0; off >>= 1) {
        if (t < off) s[t] += s[t + off];
        __syncthreads();
    }
    if (t == 0) bsum[blockIdx.x] = s[0];
}
// exclusive scan of block sums (nb <= 512), single block of 512 threads
__global__ void k_scan_bsums(int* __restrict__ bsum, int nb) {
    __shared__ int s[512];
    int t = threadIdx.x;
    int v = (t < nb) ? bsum[t] : 0;
    s[t] = v;
    __syncthreads();
    for (int off = 1; off < 512; off <<= 1) {
        int u = (t >= off) ? s[t - off] : 0;
        __syncthreads();
        s[t] += u;
        __syncthreads();
    }
    if (t < nb) bsum[t] = s[t] - v;  // exclusive
}
__global__ void k_row_ptr(const int* __restrict__ deg, const int* __restrict__ bsum,
                          int* __restrict__ row_ptr) {
    __shared__ int s[256];
    int t = threadIdx.x;
    int i = blockIdx.x * 256 + t;
    int v = (i < N_NODES) ? deg[i] : 0;
    s[t] = v;
    __syncthreads();
    for (int off = 1; off < 256; off <<= 1) {
        int u = (t >= off) ? s[t - off] : 0;
        __syncthreads();
        s[t] += u;
        __syncthreads();
    }
    if (i < N_NODES) row_ptr[i] = bsum[blockIdx.x] + s[t] - v;  // exclusive
    if (blockIdx.x == 0 && t == 0) row_ptr[N_NODES] = N_EDGES;
}
__global__ void k_scatter(const int* __restrict__ src, const int* __restrict__ dst,
                          const int* __restrict__ row_ptr, int* __restrict__ cursor,
                          int* __restrict__ col) {
    int e = blockIdx.x * 256 + threadIdx.x;
    if (e < N_EDGES) {
        int d = dst[e];
        int p = atomicAdd(&cursor[d], 1);
        col[row_ptr[d] + p] = src[e];
    }
}

// ================= GEMM: C[M x 256] = act(A)[M x 256] @ B[256 x 256] =================
// 64x64 tile, 256 threads, 4x4 micro-tile, K-step 16.
// BN=true: A element a[r][c] -> relu(a*scale[c]+shift[c]) applied on LDS stage.
template <typename OutT, bool BN>
__global__ void k_gemm(const float* __restrict__ A, const float* __restrict__ B,
                       OutT* __restrict__ C, int M,
                       const float* __restrict__ scale, const float* __restrict__ shift) {
    __shared__ float As[16][64];
    __shared__ float Bs[16][64];
    const int tid = threadIdx.x;
    const int tx = tid & 15, ty = tid >> 4;
    const int row0 = blockIdx.y * 64;
    const int col0 = blockIdx.x * 64;

    const int lm = tid >> 2;          // 0..63 (A row within tile)
    const int lk = (tid & 3) * 4;     // 0,4,8,12 (A k quad)
    const int bk = tid >> 4;          // 0..15 (B k)
    const int bn = (tid & 15) * 4;    // 0..60 (B col quad)

    float acc[4][4] = {};
    for (int k0 = 0; k0 < 256; k0 += 16) {
        float4 av = make_float4(0.f, 0.f, 0.f, 0.f);
        int ar = row0 + lm;
        if (ar < M) av = *(const float4*)(A + (size_t)ar * 256 + k0 + lk);
        if (BN) {
            float4 sc = *(const float4*)(scale + k0 + lk);
            float4 sh = *(const float4*)(shift + k0 + lk);
            av.x = fmaxf(av.x * sc.x + sh.x, 0.f);
            av.y = fmaxf(av.y * sc.y + sh.y, 0.f);
            av.z = fmaxf(av.z * sc.z + sh.z, 0.f);
            av.w = fmaxf(av.w * sc.w + sh.w, 0.f);
        }
        As[lk + 0][lm] = av.x; As[lk + 1][lm] = av.y;
        As[lk + 2][lm] = av.z; As[lk + 3][lm] = av.w;
        *(float4*)(&Bs[bk][bn]) = *(const float4*)(B + (size_t)(k0 + bk) * 256 + col0 + bn);
        __syncthreads();
#pragma unroll
        for (int k = 0; k < 16; ++k) {
            float a0 = As[k][ty * 4 + 0], a1 = As[k][ty * 4 + 1];
            float a2 = As[k][ty * 4 + 2], a3 = As[k][ty * 4 + 3];
            float b0 = Bs[k][tx * 4 + 0], b1 = Bs[k][tx * 4 + 1];
            float b2 = Bs[k][tx * 4 + 2], b3 = Bs[k][tx * 4 + 3];
            acc[0][0] += a0 * b0; acc[0][1] += a0 * b1; acc[0][2] += a0 * b2; acc[0][3] += a0 * b3;
            acc[1][0] += a1 * b0; acc[1][1] += a1 * b1; acc[1][2] += a1 * b2; acc[1][3] += a1 * b3;
            acc[2][0] += a2 * b0; acc[2][1] += a2 * b1; acc[2][2] += a2 * b2; acc[2][3] += a2 * b3;
            acc[3][0] += a3 * b0; acc[3][1] += a3 * b1; acc[3][2] += a3 * b2; acc[3][3] += a3 * b3;
        }
        __syncthreads();
    }
#pragma unroll
    for (int i = 0; i < 4; ++i) {
        int r = row0 + ty * 4 + i;
        if (r < M) {
#pragma unroll
            for (int j = 0; j < 4; ++j)
                store_val(C + (size_t)r * 256 + col0 + tx * 4 + j, acc[i][j]);
        }
    }
}

// ================= CSR aggregation (gather, no atomics) =================
// out[d] = dinv[d]^2 * xw[d] + sum_{s in col[row_ptr[d]:row_ptr[d+1]]} dinv[d]*dinv[s]*xw[s] + bias
// one wave per node, lane holds float4 (4 channels)
__global__ void k_agg_csr(const float* __restrict__ xw, const float* __restrict__ dinv,
                          const int* __restrict__ row_ptr, const int* __restrict__ col,
                          const float* __restrict__ bias, float* __restrict__ out) {
    int wave = threadIdx.x >> 6, lane = threadIdx.x & 63;
    int node = blockIdx.x * 4 + wave;
    if (node >= N_NODES) return;
    int beg = row_ptr[node], end = row_ptr[node + 1];
    float dv = dinv[node];
    const float4* xwv = (const float4*)xw;
    float4 x = xwv[(size_t)node * 64 + lane];
    float s2 = dv * dv;
    float4 acc;
    acc.x = s2 * x.x; acc.y = s2 * x.y; acc.z = s2 * x.z; acc.w = s2 * x.w;
    for (int i = beg; i < end; ++i) {
        int s = col[i];
        float w = dv * dinv[s];
        float4 m = xwv[(size_t)s * 64 + lane];
        acc.x += w * m.x; acc.y += w * m.y; acc.z += w * m.z; acc.w += w * m.w;
    }
    float4 bv = ((const float4*)bias)[lane];
    acc.x += bv.x; acc.y += bv.y; acc.z += bv.z; acc.w += bv.w;
    ((float4*)out)[(size_t)node * 64 + lane] = acc;
}

// ================= batch norm stats =================
__global__ void k_bn_zero(float* bnsum, float* bnsumsq) {
    int c = threadIdx.x;
    bnsum[c] = 0.f; bnsumsq[c] = 0.f;
}
__global__ void k_bn_stats(const float* __restrict__ x, float* bnsum, float* bnsumsq) {
    int c = threadIdx.x;
    int r0 = blockIdx.x * 256;
    int rend = min(r0 + 256, N_NODES);
    float s = 0.f, q = 0.f;
    for (int r = r0; r < rend; ++r) {
        float v = x[(size_t)r * CH + c];
        s += v; q += v * v;
    }
    atomicAdd(&bnsum[c], s);
    atomicAdd(&bnsumsq[c], q);
}
__global__ void k_bn_finalize(const float* bnsum, const float* bnsumsq,
                              const float* __restrict__ g, const float* __restrict__ be,
                              float* scale, float* shift) {
    int c = threadIdx.x;
    float mu = bnsum[c] * (1.0f / N_NODES);
    float var = bnsumsq[c] * (1.0f / N_NODES) - mu * mu;
    float sc = g[c] * rsqrtf(var + EPS);
    scale[c] = sc;
    shift[c] = be[c] - mu * sc;
}

// ================= edge scoring =================
template <typename T>
__global__ void k_edge_score(const T* __restrict__ u, const T* __restrict__ v,
                             const int* __restrict__ src, const int* __restrict__ dst,
                             const int* __restrict__ neg, const float* __restrict__ fc1_b,
                             const float* __restrict__ fc2_w, const float* __restrict__ fc2_b,
                             float* __restrict__ out) {
    int wave = threadIdx.x >> 6, lane = threadIdx.x & 63;
    int e = blockIdx.x * 4 + wave;
    if (e >= N_EDGES) return;
    int s = src[e], d = dst[e], g = neg[e];
    const T* us = u + (size_t)s * CH;
    const T* vd = v + (size_t)d * CH;
    const T* vg = v + (size_t)g * CH;
    float accp = 0.f, accn = 0.f;
#pragma unroll
    for (int j = 0; j < 4; ++j) {
        int c = lane + j * 64;
        float t = load_val(us + c) + fc1_b[c];
        float hp = t + load_val(vd + c); hp = hp > 0.f ? hp : 0.f;
        float hn = t + load_val(vg + c); hn = hn > 0.f ? hn : 0.f;
        float w = fc2_w[c];
        accp += hp * w;
        accn += hn * w;
    }
#pragma unroll
    for (int off = 32; off > 0; off >>= 1) {
        accp += __shfl_down(accp, off, 64);
        accn += __shfl_down(accn, off, 64);
    }
    if (lane == 0) {
        float bb = fc2_b[0];
        out[e] = 1.0f / (1.0f + expf(-(accp + bb)));
        out[N_EDGES + e] = 1.0f / (1.0f + expf(-(accn + bb)));
    }
}

extern "C" void kernel_launch(void* const* d_in, const int* in_sizes, int n_in,
                              void* d_out, int out_size, void* d_ws, size_t ws_size,
                              hipStream_t stream) {
    const float* node_feat = (const float*)d_in[0];
    const int* src = (const int*)d_in[1];
    const int* dst = (const int*)d_in[2];
    const int* neg = (const int*)d_in[3];
    const float* W1 = (const float*)d_in[4];  const float* b1 = (const float*)d_in[5];
    const float* W2 = (const float*)d_in[6];  const float* b2 = (const float*)d_in[7];
    const float* W3 = (const float*)d_in[8];  const float* b3 = (const float*)d_in[9];
    const float* g1 = (const float*)d_in[10]; const float* be1 = (const float*)d_in[11];
    const float* g2 = (const float*)d_in[12]; const float* be2 = (const float*)d_in[13];
    const float* fc1_w = (const float*)d_in[14]; const float* fc1_b = (const float*)d_in[15];
    const float* fc2_w = (const float*)d_in[16]; const float* fc2_b = (const float*)d_in[17];
    float* out = (float*)d_out;

    const size_t NF = (size_t)N_NODES * CH;  // 25,600,000
    float* bufA = (float*)d_ws;              // xw
    float* bufB = bufA + NF;                 // aggregated / z
    float* dinv = bufB + NF;
    float* bnsum = dinv + N_NODES;
    float* bnsumsq = bnsum + CH;
    float* scale = bnsumsq + CH;
    float* shift = scale + CH;
    int* ideg = (int*)(shift + CH);          // N
    int* cursor = ideg + N_NODES;            // N
    int* row_ptr = cursor + N_NODES;         // N+1
    int* col = row_ptr + N_NODES + 1;        // E
    int* bsum = col + N_EDGES;               // 512
    // pad to 16B
    size_t off_floats = ((size_t)((bsum + 512) - (int*)d_ws) + 3) & ~(size_t)3;
    float* bufC = (float*)d_ws + off_floats; // fp32 u,v if ws permits

    size_t need_f32 = (off_floats + 2 * NF) * 4;
    bool uv_f32 = ws_size >= need_f32;

    dim3 gemmGrid(4, (N_NODES + 63) / 64);
    int nodeBlocks = (N_NODES + 255) / 256;   // 391
    int edgeBlocks = (N_EDGES + 255) / 256;
    int aggBlocks = (N_NODES + 3) / 4;        // wave per node

    // ---- CSR build + dinv ----
    k_zero_int<<<nodeBlocks, 256, 0, stream>>>(ideg, N_NODES);
    k_zero_int<<<nodeBlocks, 256, 0, stream>>>(cursor, N_NODES);
    k_count_deg<<<edgeBlocks, 256, 0, stream>>>(dst, ideg);
    k_dinv_from_deg<<<nodeBlocks, 256, 0, stream>>>(ideg, dinv);
    k_block_sums<<<nodeBlocks, 256, 0, stream>>>(ideg, bsum);
    k_scan_bsums<<<1, 512, 0, stream>>>(bsum, nodeBlocks);
    k_row_ptr<<<nodeBlocks, 256, 0, stream>>>(ideg, bsum, row_ptr);
    k_scatter<<<edgeBlocks, 256, 0, stream>>>(src, dst, row_ptr, cursor, col);

    // ---- layer 1 ----
    k_gemm<float, false><<<gemmGrid, 256, 0, stream>>>(node_feat, W1, bufA, N_NODES, nullptr, nullptr);
    k_agg_csr<<<aggBlocks, 256, 0, stream>>>(bufA, dinv, row_ptr, col, b1, bufB);
    k_bn_zero<<<1, 256, 0, stream>>>(bnsum, bnsumsq);
    k_bn_stats<<<nodeBlocks, 256, 0, stream>>>(bufB, bnsum, bnsumsq);
    k_bn_finalize<<<1, 256, 0, stream>>>(bnsum, bnsumsq, g1, be1, scale, shift);

    // ---- layer 2 (BN1+relu fused into A-load) ----
    k_gemm<float, true><<<gemmGrid, 256, 0, stream>>>(bufB, W2, bufA, N_NODES, scale, shift);
    k_agg_csr<<<aggBlocks, 256, 0, stream>>>(bufA, dinv, row_ptr, col, b2, bufB);
    k_bn_zero<<<1, 256, 0, stream>>>(bnsum, bnsumsq);
    k_bn_stats<<<nodeBlocks, 256, 0, stream>>>(bufB, bnsum, bnsumsq);
    k_bn_finalize<<<1, 256, 0, stream>>>(bnsum, bnsumsq, g2, be2, scale, shift);

    // ---- layer 3 (BN2+relu fused into A-load; no BN after) ----
    k_gemm<float, true><<<gemmGrid, 256, 0, stream>>>(bufB, W3, bufA, N_NODES, scale, shift);
    k_agg_csr<<<aggBlocks, 256, 0, stream>>>(bufA, dinv, row_ptr, col, b3, bufB);  // z in bufB

    // ---- link predictor: u = z @ fc1_w[:256], v = z @ fc1_w[256:] ----
    int scoreBlocks = (N_EDGES + 3) / 4;
    if (uv_f32) {
        float* u = bufC;
        float* v = bufC + NF;
        k_gemm<float, false><<<gemmGrid, 256, 0, stream>>>(bufB, fc1_w, u, N_NODES, nullptr, nullptr);
        k_gemm<float, false><<<gemmGrid, 256, 0, stream>>>(bufB, fc1_w + CH * CH, v, N_NODES, nullptr, nullptr);
        k_edge_score<float><<<scoreBlocks, 256, 0, stream>>>(u, v, src, dst, neg,
                                                             fc1_b, fc2_w, fc2_b, out);
    } else {
        // bf16 fallback: u,v overwrite bufA (xw3 is dead)
        bf16* u = (bf16*)bufA;
        bf16* v = u + NF;
        k_gemm<bf16, false><<<gemmGrid, 256, 0, stream>>>(bufB, fc1_w, u, N_NODES, nullptr, nullptr);
        k_gemm<bf16, false><<<gemmGrid, 256, 0, stream>>>(bufB, fc1_w + CH * CH, v, N_NODES, nullptr, nullptr);
        k_edge_score<bf16><<<scoreBlocks, 256, 0, stream>>>(u, v, src, dst, neg,
                                                            fc1_b, fc2_w, fc2_b, out);
    }
}

// Round 3
// 916.161 us; speedup vs baseline: 2.4465x; 1.6716x over previous
//
#include <hip/hip_runtime.h>
#include <hip/hip_bf16.h>

#define N_NODES 100000
#define N_EDGES 300000
#define CH 256
#define EPS 1e-5f

typedef __hip_bfloat16 bf16;
typedef __attribute__((ext_vector_type(8))) short bf16x8_t;  // 8 bf16 (4 VGPRs)
typedef __attribute__((ext_vector_type(4))) float f32x4_t;   // 4 fp32 acc

__device__ __forceinline__ void store_val(float* p, float v) { *p = v; }
__device__ __forceinline__ void store_val(bf16* p, float v) { *p = __float2bfloat16(v); }
__device__ __forceinline__ float load_val(const float* p) { return *p; }
__device__ __forceinline__ float load_val(const bf16* p) { return __bfloat162float(*p); }
__device__ __forceinline__ unsigned short f2bf(float f) {
    bf16 h = __float2bfloat16(f);
    return __builtin_bit_cast(unsigned short, h);
}

__device__ __forceinline__ void async_copy16(const void* g, void* l) {
    __builtin_amdgcn_global_load_lds((const __attribute__((address_space(1))) void*)g,
                                     (__attribute__((address_space(3))) void*)l, 16, 0, 0);
}

// ================= CSR build =================
__global__ void k_zero_int(int* __restrict__ p, int n) {
    int i = blockIdx.x * 256 + threadIdx.x;
    if (i < n) p[i] = 0;
}
__global__ void k_count_deg(const int* __restrict__ dst, int* __restrict__ deg) {
    int e = blockIdx.x * 256 + threadIdx.x;
    if (e < N_EDGES) atomicAdd(&deg[dst[e]], 1);
}
__global__ void k_dinv_from_deg(const int* __restrict__ deg, float* __restrict__ dinv) {
    int i = blockIdx.x * 256 + threadIdx.x;
    if (i < N_NODES) dinv[i] = rsqrtf((float)(deg[i] + 1));  // +1 self loop
}
__global__ void k_block_sums(const int* __restrict__ deg, int* __restrict__ bsum) {
    __shared__ int s[256];
    int t = threadIdx.x;
    int i = blockIdx.x * 256 + t;
    s[t] = (i < N_NODES) ? deg[i] : 0;
    __syncthreads();
    for (int off = 128; off > 0; off >>= 1) {
        if (t < off) s[t] += s[t + off];
        __syncthreads();
    }
    if (t == 0) bsum[blockIdx.x] = s[0];
}
__global__ void k_scan_bsums(int* __restrict__ bsum, int nb) {
    __shared__ int s[512];
    int t = threadIdx.x;
    int v = (t < nb) ? bsum[t] : 0;
    s[t] = v;
    __syncthreads();
    for (int off = 1; off < 512; off <<= 1) {
        int u = (t >= off) ? s[t - off] : 0;
        __syncthreads();
        s[t] += u;
        __syncthreads();
    }
    if (t < nb) bsum[t] = s[t] - v;  // exclusive
}
__global__ void k_row_ptr(const int* __restrict__ deg, const int* __restrict__ bsum,
                          int* __restrict__ row_ptr) {
    __shared__ int s[256];
    int t = threadIdx.x;
    int i = blockIdx.x * 256 + t;
    int v = (i < N_NODES) ? deg[i] : 0;
    s[t] = v;
    __syncthreads();
    for (int off = 1; off < 256; off <<= 1) {
        int u = (t >= off) ? s[t - off] : 0;
        __syncthreads();
        s[t] += u;
        __syncthreads();
    }
    if (i < N_NODES) row_ptr[i] = bsum[blockIdx.x] + s[t] - v;  // exclusive
    if (blockIdx.x == 0 && t == 0) row_ptr[N_NODES] = N_EDGES;
}
__global__ void k_scatter(const int* __restrict__ src, const int* __restrict__ dst,
                          const int* __restrict__ row_ptr, int* __restrict__ cursor,
                          int* __restrict__ col) {
    int e = blockIdx.x * 256 + threadIdx.x;
    if (e < N_EDGES) {
        int d = dst[e];
        int p = atomicAdd(&cursor[d], 1);
        col[row_ptr[d] + p] = src[e];
    }
}

// ================= weight transpose+cast: Wt[n][k] = W[row_off+k][n] =================
__global__ void k_transpose_cast(const float* __restrict__ W, bf16* __restrict__ Wt,
                                 int row_off) {
    int idx = blockIdx.x * 256 + threadIdx.x;  // 65536
    int n = idx >> 8, k = idx & 255;
    Wt[(size_t)n * 256 + k] = __float2bfloat16(W[(size_t)(row_off + k) * 256 + n]);
}

// ================= casts =================
__global__ void k_cast_bf16_v4(const float* __restrict__ x, unsigned short* __restrict__ y) {
    int i = blockIdx.x * 256 + threadIdx.x;  // over NF/4
    float4 v = ((const float4*)x)[i];
    ushort4 o;
    o.x = f2bf(v.x); o.y = f2bf(v.y); o.z = f2bf(v.z); o.w = f2bf(v.w);
    ((ushort4*)y)[i] = o;
}
__global__ void k_bn_relu_cast_v4(const float* __restrict__ x, const float* __restrict__ scale,
                                  const float* __restrict__ shift, unsigned short* __restrict__ y) {
    int i = blockIdx.x * 256 + threadIdx.x;  // over NF/4
    float4 v = ((const float4*)x)[i];
    int c = (i & 63) * 4;
    float4 sc = *(const float4*)(scale + c);
    float4 sh = *(const float4*)(shift + c);
    ushort4 o;
    o.x = f2bf(fmaxf(v.x * sc.x + sh.x, 0.f));
    o.y = f2bf(fmaxf(v.y * sc.y + sh.y, 0.f));
    o.z = f2bf(fmaxf(v.z * sc.z + sh.z, 0.f));
    o.w = f2bf(fmaxf(v.w * sc.w + sh.w, 0.f));
    ((ushort4*)y)[i] = o;
}

// ================= bf16 MFMA GEMM: C[M x 256] = A[M x 256] @ Bt[256 x 256]^T =================
// A: bf16 row-major [M][256]. Bt: bf16 [N=256][K=256] (transposed weights).
// 128x128 tile, BK=64, 4 waves (2x2), each wave 64x64 via 4x4 of 16x16x32 MFMA.
// LDS chunk swizzle: LDS[r][chunk c] holds global k-chunk (c ^ (r&7)) -> ds_read_b128 2-way max.
template <typename OutT>
__global__ __launch_bounds__(256) void k_gemm_mfma(const bf16* __restrict__ A,
                                                   const bf16* __restrict__ Bt,
                                                   OutT* __restrict__ C, int M) {
    __shared__ bf16 As[128 * 64];
    __shared__ bf16 Bs[128 * 64];
    const int tid = threadIdx.x;
    const int lane = tid & 63;
    const int w = tid >> 6;
    const int wr = w >> 1, wc = w & 1;
    const int lr = lane & 15, quad = lane >> 4;
    const int row0 = blockIdx.y * 128;
    const int col0 = blockIdx.x * 128;

    f32x4_t acc[4][4] = {};

    for (int k0 = 0; k0 < 256; k0 += 64) {
        // stage: 1024 chunks of 16B each for A and Bt
#pragma unroll
        for (int i = 0; i < 4; ++i) {
            int j = i * 256 + tid;
            int r = j >> 3, c = j & 7;
            int gk = ((c ^ (r & 7)) << 3);
            int gr = row0 + r; gr = gr < M ? gr : M - 1;
            async_copy16(A + (size_t)gr * 256 + k0 + gk, (void*)(As + j * 8));
            async_copy16(Bt + (size_t)(col0 + r) * 256 + k0 + gk, (void*)(Bs + j * 8));
        }
        __syncthreads();
#pragma unroll
        for (int ks = 0; ks < 2; ++ks) {
            bf16x8_t af[4], bfr[4];
#pragma unroll
            for (int mi = 0; mi < 4; ++mi) {
                int m = wr * 64 + mi * 16 + lr;
                int c = (ks * 4 + quad) ^ (m & 7);
                af[mi] = *(const bf16x8_t*)(As + m * 64 + c * 8);
            }
#pragma unroll
            for (int ni = 0; ni < 4; ++ni) {
                int n = wc * 64 + ni * 16 + lr;
                int c = (ks * 4 + quad) ^ (n & 7);
                bfr[ni] = *(const bf16x8_t*)(Bs + n * 64 + c * 8);
            }
#pragma unroll
            for (int mi = 0; mi < 4; ++mi)
#pragma unroll
                for (int ni = 0; ni < 4; ++ni)
                    acc[mi][ni] = __builtin_amdgcn_mfma_f32_16x16x32_bf16(
                        af[mi], bfr[ni], acc[mi][ni], 0, 0, 0);
        }
        __syncthreads();
    }
    // epilogue: C/D layout col=lane&15, row=quad*4+reg
#pragma unroll
    for (int mi = 0; mi < 4; ++mi) {
#pragma unroll
        for (int r = 0; r < 4; ++r) {
            int row = row0 + wr * 64 + mi * 16 + quad * 4 + r;
            if (row < M) {
#pragma unroll
                for (int ni = 0; ni < 4; ++ni) {
                    int colg = col0 + wc * 64 + ni * 16 + lr;
                    store_val(C + (size_t)row * 256 + colg, acc[mi][ni][r]);
                }
            }
        }
    }
}

// ================= CSR aggregation (gather, no atomics) =================
__global__ void k_agg_csr(const float* __restrict__ xw, const float* __restrict__ dinv,
                          const int* __restrict__ row_ptr, const int* __restrict__ col,
                          const float* __restrict__ bias, float* __restrict__ out) {
    int wave = threadIdx.x >> 6, lane = threadIdx.x & 63;
    int node = blockIdx.x * 4 + wave;
    if (node >= N_NODES) return;
    int beg = row_ptr[node], end = row_ptr[node + 1];
    float dv = dinv[node];
    const float4* xwv = (const float4*)xw;
    float4 x = xwv[(size_t)node * 64 + lane];
    float s2 = dv * dv;
    float4 acc;
    acc.x = s2 * x.x; acc.y = s2 * x.y; acc.z = s2 * x.z; acc.w = s2 * x.w;
    for (int i = beg; i < end; ++i) {
        int s = col[i];
        float wgt = dv * dinv[s];
        float4 m = xwv[(size_t)s * 64 + lane];
        acc.x += wgt * m.x; acc.y += wgt * m.y; acc.z += wgt * m.z; acc.w += wgt * m.w;
    }
    float4 bv = ((const float4*)bias)[lane];
    acc.x += bv.x; acc.y += bv.y; acc.z += bv.z; acc.w += bv.w;
    ((float4*)out)[(size_t)node * 64 + lane] = acc;
}

// ================= batch norm stats =================
__global__ void k_bn_zero(float* bnsum, float* bnsumsq) {
    int c = threadIdx.x;
    bnsum[c] = 0.f; bnsumsq[c] = 0.f;
}
__global__ void k_bn_stats(const float* __restrict__ x, float* bnsum, float* bnsumsq) {
    int c = threadIdx.x;
    int r0 = blockIdx.x * 256;
    int rend = min(r0 + 256, N_NODES);
    float s = 0.f, q = 0.f;
    for (int r = r0; r < rend; ++r) {
        float v = x[(size_t)r * CH + c];
        s += v; q += v * v;
    }
    atomicAdd(&bnsum[c], s);
    atomicAdd(&bnsumsq[c], q);
}
__global__ void k_bn_finalize(const float* bnsum, const float* bnsumsq,
                              const float* __restrict__ g, const float* __restrict__ be,
                              float* scale, float* shift) {
    int c = threadIdx.x;
    float mu = bnsum[c] * (1.0f / N_NODES);
    float var = bnsumsq[c] * (1.0f / N_NODES) - mu * mu;
    float sc = g[c] * rsqrtf(var + EPS);
    scale[c] = sc;
    shift[c] = be[c] - mu * sc;
}

// ================= edge scoring =================
template <typename T>
__global__ void k_edge_score(const T* __restrict__ u, const T* __restrict__ v,
                             const int* __restrict__ src, const int* __restrict__ dst,
                             const int* __restrict__ neg, const float* __restrict__ fc1_b,
                             const float* __restrict__ fc2_w, const float* __restrict__ fc2_b,
                             float* __restrict__ out) {
    int wave = threadIdx.x >> 6, lane = threadIdx.x & 63;
    int e = blockIdx.x * 4 + wave;
    if (e >= N_EDGES) return;
    int s = src[e], d = dst[e], g = neg[e];
    const T* us = u + (size_t)s * CH;
    const T* vd = v + (size_t)d * CH;
    const T* vg = v + (size_t)g * CH;
    float accp = 0.f, accn = 0.f;
#pragma unroll
    for (int j = 0; j < 4; ++j) {
        int c = lane + j * 64;
        float t = load_val(us + c) + fc1_b[c];
        float hp = t + load_val(vd + c); hp = hp > 0.f ? hp : 0.f;
        float hn = t + load_val(vg + c); hn = hn > 0.f ? hn : 0.f;
        float wgt = fc2_w[c];
        accp += hp * wgt;
        accn += hn * wgt;
    }
#pragma unroll
    for (int off = 32; off > 0; off >>= 1) {
        accp += __shfl_down(accp, off, 64);
        accn += __shfl_down(accn, off, 64);
    }
    if (lane == 0) {
        float bb = fc2_b[0];
        out[e] = 1.0f / (1.0f + expf(-(accp + bb)));
        out[N_EDGES + e] = 1.0f / (1.0f + expf(-(accn + bb)));
    }
}

extern "C" void kernel_launch(void* const* d_in, const int* in_sizes, int n_in,
                              void* d_out, int out_size, void* d_ws, size_t ws_size,
                              hipStream_t stream) {
    const float* node_feat = (const float*)d_in[0];
    const int* src = (const int*)d_in[1];
    const int* dst = (const int*)d_in[2];
    const int* neg = (const int*)d_in[3];
    const float* W1 = (const float*)d_in[4];  const float* b1 = (const float*)d_in[5];
    const float* W2 = (const float*)d_in[6];  const float* b2 = (const float*)d_in[7];
    const float* W3 = (const float*)d_in[8];  const float* b3 = (const float*)d_in[9];
    const float* g1 = (const float*)d_in[10]; const float* be1 = (const float*)d_in[11];
    const float* g2 = (const float*)d_in[12]; const float* be2 = (const float*)d_in[13];
    const float* fc1_w = (const float*)d_in[14]; const float* fc1_b = (const float*)d_in[15];
    const float* fc2_w = (const float*)d_in[16]; const float* fc2_b = (const float*)d_in[17];
    float* out = (float*)d_out;

    const size_t NF = (size_t)N_NODES * CH;  // 25,600,000
    float* bufA = (float*)d_ws;              // fp32 xw (GEMM out)
    float* bufB = bufA + NF;                 // fp32 aggregated / z
    bf16* Xbf = (bf16*)(bufB + NF);          // bf16 activations (NF)
    bf16* wt1 = Xbf + NF;                    // 65536 each
    bf16* wt2 = wt1 + 65536;
    bf16* wt3 = wt2 + 65536;
    bf16* wtu = wt3 + 65536;
    bf16* wtv = wtu + 65536;
    float* dinv = (float*)(wtv + 65536);
    float* bnsum = dinv + N_NODES;
    float* bnsumsq = bnsum + CH;
    float* scale = bnsumsq + CH;
    float* shift = scale + CH;
    int* ideg = (int*)(shift + CH);
    int* cursor = ideg + N_NODES;
    int* row_ptr = cursor + N_NODES;
    int* col = row_ptr + N_NODES + 1;
    int* bsum = col + N_EDGES;
    size_t off_floats = ((size_t)((bsum + 512) - (int*)d_ws) + 3) & ~(size_t)3;
    float* bufC = (float*)d_ws + off_floats;  // fp32 u,v if ws permits
    size_t need_f32 = (off_floats + 2 * NF) * 4;
    bool uv_f32 = ws_size >= need_f32;

    dim3 gemmGrid(2, (N_NODES + 127) / 128);  // 2 x 782
    int nodeBlocks = (N_NODES + 255) / 256;
    int edgeBlocks = (N_EDGES + 255) / 256;
    int aggBlocks = (N_NODES + 3) / 4;
    int v4Blocks = (int)(NF / 4 / 256);       // 25000
    int scoreBlocks = (N_EDGES + 3) / 4;

    // ---- CSR build + dinv ----
    k_zero_int<<<nodeBlocks, 256, 0, stream>>>(ideg, N_NODES);
    k_zero_int<<<nodeBlocks, 256, 0, stream>>>(cursor, N_NODES);
    k_count_deg<<<edgeBlocks, 256, 0, stream>>>(dst, ideg);
    k_dinv_from_deg<<<nodeBlocks, 256, 0, stream>>>(ideg, dinv);
    k_block_sums<<<nodeBlocks, 256, 0, stream>>>(ideg, bsum);
    k_scan_bsums<<<1, 512, 0, stream>>>(bsum, nodeBlocks);
    k_row_ptr<<<nodeBlocks, 256, 0, stream>>>(ideg, bsum, row_ptr);
    k_scatter<<<edgeBlocks, 256, 0, stream>>>(src, dst, row_ptr, cursor, col);

    // ---- weight transpose+cast (bf16 [N][K]) ----
    k_transpose_cast<<<256, 256, 0, stream>>>(W1, wt1, 0);
    k_transpose_cast<<<256, 256, 0, stream>>>(W2, wt2, 0);
    k_transpose_cast<<<256, 256, 0, stream>>>(W3, wt3, 0);
    k_transpose_cast<<<256, 256, 0, stream>>>(fc1_w, wtu, 0);
    k_transpose_cast<<<256, 256, 0, stream>>>(fc1_w, wtv, 256);

    // ---- layer 1 ----
    k_cast_bf16_v4<<<v4Blocks, 256, 0, stream>>>(node_feat, (unsigned short*)Xbf);
    k_gemm_mfma<float><<<gemmGrid, 256, 0, stream>>>(Xbf, wt1, bufA, N_NODES);
    k_agg_csr<<<aggBlocks, 256, 0, stream>>>(bufA, dinv, row_ptr, col, b1, bufB);
    k_bn_zero<<<1, 256, 0, stream>>>(bnsum, bnsumsq);
    k_bn_stats<<<nodeBlocks, 256, 0, stream>>>(bufB, bnsum, bnsumsq);
    k_bn_finalize<<<1, 256, 0, stream>>>(bnsum, bnsumsq, g1, be1, scale, shift);
    k_bn_relu_cast_v4<<<v4Blocks, 256, 0, stream>>>(bufB, scale, shift, (unsigned short*)Xbf);

    // ---- layer 2 ----
    k_gemm_mfma<float><<<gemmGrid, 256, 0, stream>>>(Xbf, wt2, bufA, N_NODES);
    k_agg_csr<<<aggBlocks, 256, 0, stream>>>(bufA, dinv, row_ptr, col, b2, bufB);
    k_bn_zero<<<1, 256, 0, stream>>>(bnsum, bnsumsq);
    k_bn_stats<<<nodeBlocks, 256, 0, stream>>>(bufB, bnsum, bnsumsq);
    k_bn_finalize<<<1, 256, 0, stream>>>(bnsum, bnsumsq, g2, be2, scale, shift);
    k_bn_relu_cast_v4<<<v4Blocks, 256, 0, stream>>>(bufB, scale, shift, (unsigned short*)Xbf);

    // ---- layer 3 ----
    k_gemm_mfma<float><<<gemmGrid, 256, 0, stream>>>(Xbf, wt3, bufA, N_NODES);
    k_agg_csr<<<aggBlocks, 256, 0, stream>>>(bufA, dinv, row_ptr, col, b3, bufB);  // z fp32

    // ---- link predictor ----
    k_cast_bf16_v4<<<v4Blocks, 256, 0, stream>>>(bufB, (unsigned short*)Xbf);  // z -> bf16
    if (uv_f32) {
        float* u = bufC;
        float* v = bufC + NF;
        k_gemm_mfma<float><<<gemmGrid, 256, 0, stream>>>(Xbf, wtu, u, N_NODES);
        k_gemm_mfma<float><<<gemmGrid, 256, 0, stream>>>(Xbf, wtv, v, N_NODES);
        k_edge_score<float><<<scoreBlocks, 256, 0, stream>>>(u, v, src, dst, neg,
                                                             fc1_b, fc2_w, fc2_b, out);
    } else {
        bf16* u = (bf16*)bufA;  // xw3 dead
        bf16* v = u + NF;
        k_gemm_mfma<bf16><<<gemmGrid, 256, 0, stream>>>(Xbf, wtu, u, N_NODES);
        k_gemm_mfma<bf16><<<gemmGrid, 256, 0, stream>>>(Xbf, wtv, v, N_NODES);
        k_edge_score<bf16><<<scoreBlocks, 256, 0, stream>>>(u, v, src, dst, neg,
                                                            fc1_b, fc2_w, fc2_b, out);
    }
}

// Round 4
// 889.187 us; speedup vs baseline: 2.5207x; 1.0303x over previous
//
#include <hip/hip_runtime.h>
#include <hip/hip_bf16.h>

#define N_NODES 100000
#define N_EDGES 300000
#define CH 256
#define EPS 1e-5f

typedef __hip_bfloat16 bf16;
typedef __attribute__((ext_vector_type(8))) short bf16x8_t;  // 8 bf16 (4 VGPRs)
typedef __attribute__((ext_vector_type(4))) float f32x4_t;   // 4 fp32 acc

__device__ __forceinline__ void store_val(float* p, float v) { *p = v; }
__device__ __forceinline__ void store_val(bf16* p, float v) { *p = __float2bfloat16(v); }
__device__ __forceinline__ unsigned short f2bf(float f) {
    bf16 h = __float2bfloat16(f);
    return __builtin_bit_cast(unsigned short, h);
}
__device__ __forceinline__ float bf2f(unsigned short u) {
    unsigned int x = ((unsigned int)u) << 16;  // exact widening
    return __builtin_bit_cast(float, x);
}

__device__ __forceinline__ void async_copy16(const void* g, void* l) {
    __builtin_amdgcn_global_load_lds((const __attribute__((address_space(1))) void*)g,
                                     (__attribute__((address_space(3))) void*)l, 16, 0, 0);
}

// ================= CSR build =================
__global__ void k_zero_int(int* __restrict__ p, int n) {
    int i = blockIdx.x * 256 + threadIdx.x;
    if (i < n) p[i] = 0;
}
__global__ void k_count_deg(const int* __restrict__ dst, int* __restrict__ deg) {
    int e = blockIdx.x * 256 + threadIdx.x;
    if (e < N_EDGES) atomicAdd(&deg[dst[e]], 1);
}
__global__ void k_dinv_from_deg(const int* __restrict__ deg, float* __restrict__ dinv) {
    int i = blockIdx.x * 256 + threadIdx.x;
    if (i < N_NODES) dinv[i] = rsqrtf((float)(deg[i] + 1));  // +1 self loop
}
__global__ void k_block_sums(const int* __restrict__ deg, int* __restrict__ bsum) {
    __shared__ int s[256];
    int t = threadIdx.x;
    int i = blockIdx.x * 256 + t;
    s[t] = (i < N_NODES) ? deg[i] : 0;
    __syncthreads();
    for (int off = 128; off > 0; off >>= 1) {
        if (t < off) s[t] += s[t + off];
        __syncthreads();
    }
    if (t == 0) bsum[blockIdx.x] = s[0];
}
__global__ void k_scan_bsums(int* __restrict__ bsum, int nb) {
    __shared__ int s[512];
    int t = threadIdx.x;
    int v = (t < nb) ? bsum[t] : 0;
    s[t] = v;
    __syncthreads();
    for (int off = 1; off < 512; off <<= 1) {
        int u = (t >= off) ? s[t - off] : 0;
        __syncthreads();
        s[t] += u;
        __syncthreads();
    }
    if (t < nb) bsum[t] = s[t] - v;  // exclusive
}
__global__ void k_row_ptr(const int* __restrict__ deg, const int* __restrict__ bsum,
                          int* __restrict__ row_ptr) {
    __shared__ int s[256];
    int t = threadIdx.x;
    int i = blockIdx.x * 256 + t;
    int v = (i < N_NODES) ? deg[i] : 0;
    s[t] = v;
    __syncthreads();
    for (int off = 1; off < 256; off <<= 1) {
        int u = (t >= off) ? s[t - off] : 0;
        __syncthreads();
        s[t] += u;
        __syncthreads();
    }
    if (i < N_NODES) row_ptr[i] = bsum[blockIdx.x] + s[t] - v;  // exclusive
    if (blockIdx.x == 0 && t == 0) row_ptr[N_NODES] = N_EDGES;
}
__global__ void k_scatter(const int* __restrict__ src, const int* __restrict__ dst,
                          const int* __restrict__ row_ptr, int* __restrict__ cursor,
                          int* __restrict__ col) {
    int e = blockIdx.x * 256 + threadIdx.x;
    if (e < N_EDGES) {
        int d = dst[e];
        int p = atomicAdd(&cursor[d], 1);
        col[row_ptr[d] + p] = src[e];
    }
}

// ================= weight transpose+cast: Wt[n][k] = W[row_off+k][n] =================
__global__ void k_transpose_cast(const float* __restrict__ W, bf16* __restrict__ Wt,
                                 int row_off) {
    int idx = blockIdx.x * 256 + threadIdx.x;  // 65536
    int n = idx >> 8, k = idx & 255;
    Wt[(size_t)n * 256 + k] = __float2bfloat16(W[(size_t)(row_off + k) * 256 + n]);
}

// ================= casts =================
__global__ void k_cast_bf16_v4(const float* __restrict__ x, unsigned short* __restrict__ y) {
    int i = blockIdx.x * 256 + threadIdx.x;  // over NF/4
    float4 v = ((const float4*)x)[i];
    ushort4 o;
    o.x = f2bf(v.x); o.y = f2bf(v.y); o.z = f2bf(v.z); o.w = f2bf(v.w);
    ((ushort4*)y)[i] = o;
}
__global__ void k_bn_relu_cast_v4(const float* __restrict__ x, const float* __restrict__ scale,
                                  const float* __restrict__ shift, unsigned short* __restrict__ y) {
    int i = blockIdx.x * 256 + threadIdx.x;  // over NF/4
    float4 v = ((const float4*)x)[i];
    int c = (i & 63) * 4;
    float4 sc = *(const float4*)(scale + c);
    float4 sh = *(const float4*)(shift + c);
    ushort4 o;
    o.x = f2bf(fmaxf(v.x * sc.x + sh.x, 0.f));
    o.y = f2bf(fmaxf(v.y * sc.y + sh.y, 0.f));
    o.z = f2bf(fmaxf(v.z * sc.z + sh.z, 0.f));
    o.w = f2bf(fmaxf(v.w * sc.w + sh.w, 0.f));
    ((ushort4*)y)[i] = o;
}

// ================= bf16 MFMA GEMM: C[M x 256] = A[M x 256] @ Bt[256 x 256]^T =================
// 128x128 tile, BK=64, 4 waves (2x2), each wave 64x64 via 4x4 of 16x16x32 MFMA.
// LDS chunk swizzle: LDS[r][chunk c] holds global k-chunk (c ^ (r&7)) -> ds_read_b128 2-way max.
template <typename OutT>
__global__ __launch_bounds__(256) void k_gemm_mfma(const bf16* __restrict__ A,
                                                   const bf16* __restrict__ Bt,
                                                   OutT* __restrict__ C, int M) {
    __shared__ bf16 As[128 * 64];
    __shared__ bf16 Bs[128 * 64];
    const int tid = threadIdx.x;
    const int lane = tid & 63;
    const int w = tid >> 6;
    const int wr = w >> 1, wc = w & 1;
    const int lr = lane & 15, quad = lane >> 4;
    const int row0 = blockIdx.y * 128;
    const int col0 = blockIdx.x * 128;

    f32x4_t acc[4][4] = {};

    for (int k0 = 0; k0 < 256; k0 += 64) {
#pragma unroll
        for (int i = 0; i < 4; ++i) {
            int j = i * 256 + tid;
            int r = j >> 3, c = j & 7;
            int gk = ((c ^ (r & 7)) << 3);
            int gr = row0 + r; gr = gr < M ? gr : M - 1;
            async_copy16(A + (size_t)gr * 256 + k0 + gk, (void*)(As + j * 8));
            async_copy16(Bt + (size_t)(col0 + r) * 256 + k0 + gk, (void*)(Bs + j * 8));
        }
        __syncthreads();
#pragma unroll
        for (int ks = 0; ks < 2; ++ks) {
            bf16x8_t af[4], bfr[4];
#pragma unroll
            for (int mi = 0; mi < 4; ++mi) {
                int m = wr * 64 + mi * 16 + lr;
                int c = (ks * 4 + quad) ^ (m & 7);
                af[mi] = *(const bf16x8_t*)(As + m * 64 + c * 8);
            }
#pragma unroll
            for (int ni = 0; ni < 4; ++ni) {
                int n = wc * 64 + ni * 16 + lr;
                int c = (ks * 4 + quad) ^ (n & 7);
                bfr[ni] = *(const bf16x8_t*)(Bs + n * 64 + c * 8);
            }
#pragma unroll
            for (int mi = 0; mi < 4; ++mi)
#pragma unroll
                for (int ni = 0; ni < 4; ++ni)
                    acc[mi][ni] = __builtin_amdgcn_mfma_f32_16x16x32_bf16(
                        af[mi], bfr[ni], acc[mi][ni], 0, 0, 0);
        }
        __syncthreads();
    }
    // epilogue: C/D layout col=lane&15, row=quad*4+reg
#pragma unroll
    for (int mi = 0; mi < 4; ++mi) {
#pragma unroll
        for (int r = 0; r < 4; ++r) {
            int row = row0 + wr * 64 + mi * 16 + quad * 4 + r;
            if (row < M) {
#pragma unroll
                for (int ni = 0; ni < 4; ++ni) {
                    int colg = col0 + wc * 64 + ni * 16 + lr;
                    store_val(C + (size_t)row * 256 + colg, acc[mi][ni][r]);
                }
            }
        }
    }
}

// ================= CSR aggregation (bf16 xw in, fp32 out, no atomics) =================
__global__ void k_agg_csr(const unsigned short* __restrict__ xw, const float* __restrict__ dinv,
                          const int* __restrict__ row_ptr, const int* __restrict__ col,
                          const float* __restrict__ bias, float* __restrict__ out) {
    int wave = threadIdx.x >> 6, lane = threadIdx.x & 63;
    int node = blockIdx.x * 4 + wave;
    if (node >= N_NODES) return;
    int beg = row_ptr[node], end = row_ptr[node + 1];
    float dv = dinv[node];
    const ushort4* xwv = (const ushort4*)xw;
    ushort4 xr = xwv[(size_t)node * 64 + lane];
    float s2 = dv * dv;
    float4 acc;
    acc.x = s2 * bf2f(xr.x); acc.y = s2 * bf2f(xr.y);
    acc.z = s2 * bf2f(xr.z); acc.w = s2 * bf2f(xr.w);
    for (int i = beg; i < end; ++i) {
        int s = col[i];
        float wgt = dv * dinv[s];
        ushort4 m = xwv[(size_t)s * 64 + lane];
        acc.x += wgt * bf2f(m.x); acc.y += wgt * bf2f(m.y);
        acc.z += wgt * bf2f(m.z); acc.w += wgt * bf2f(m.w);
    }
    float4 bv = ((const float4*)bias)[lane];
    acc.x += bv.x; acc.y += bv.y; acc.z += bv.z; acc.w += bv.w;
    ((float4*)out)[(size_t)node * 64 + lane] = acc;
}

// ================= batch norm stats =================
__global__ void k_bn_zero(float* bnsum, float* bnsumsq) {
    int c = threadIdx.x;
    bnsum[c] = 0.f; bnsumsq[c] = 0.f;
}
__global__ void k_bn_stats(const float* __restrict__ x, float* bnsum, float* bnsumsq) {
    int c = threadIdx.x;
    int r0 = blockIdx.x * 256;
    int rend = min(r0 + 256, N_NODES);
    float s = 0.f, q = 0.f;
    for (int r = r0; r < rend; ++r) {
        float v = x[(size_t)r * CH + c];
        s += v; q += v * v;
    }
    atomicAdd(&bnsum[c], s);
    atomicAdd(&bnsumsq[c], q);
}
__global__ void k_bn_finalize(const float* bnsum, const float* bnsumsq,
                              const float* __restrict__ g, const float* __restrict__ be,
                              float* scale, float* shift) {
    int c = threadIdx.x;
    float mu = bnsum[c] * (1.0f / N_NODES);
    float var = bnsumsq[c] * (1.0f / N_NODES) - mu * mu;
    float sc = g[c] * rsqrtf(var + EPS);
    scale[c] = sc;
    shift[c] = be[c] - mu * sc;
}

// ================= edge scoring (bf16 u,v; one wave per edge; float4/lane) =================
__global__ void k_edge_score(const unsigned short* __restrict__ u,
                             const unsigned short* __restrict__ v,
                             const int* __restrict__ src, const int* __restrict__ dst,
                             const int* __restrict__ neg, const float* __restrict__ fc1_b,
                             const float* __restrict__ fc2_w, const float* __restrict__ fc2_b,
                             float* __restrict__ out) {
    int wave = threadIdx.x >> 6, lane = threadIdx.x & 63;
    int e = blockIdx.x * 4 + wave;
    if (e >= N_EDGES) return;
    int s = src[e], d = dst[e], g = neg[e];
    ushort4 uu = ((const ushort4*)(u + (size_t)s * CH))[lane];
    ushort4 vv = ((const ushort4*)(v + (size_t)d * CH))[lane];
    ushort4 gg = ((const ushort4*)(v + (size_t)g * CH))[lane];
    float4 b4 = ((const float4*)fc1_b)[lane];
    float4 w4 = ((const float4*)fc2_w)[lane];
    float t0 = bf2f(uu.x) + b4.x, t1 = bf2f(uu.y) + b4.y;
    float t2 = bf2f(uu.z) + b4.z, t3 = bf2f(uu.w) + b4.w;
    float accp = fmaxf(t0 + bf2f(vv.x), 0.f) * w4.x + fmaxf(t1 + bf2f(vv.y), 0.f) * w4.y +
                 fmaxf(t2 + bf2f(vv.z), 0.f) * w4.z + fmaxf(t3 + bf2f(vv.w), 0.f) * w4.w;
    float accn = fmaxf(t0 + bf2f(gg.x), 0.f) * w4.x + fmaxf(t1 + bf2f(gg.y), 0.f) * w4.y +
                 fmaxf(t2 + bf2f(gg.z), 0.f) * w4.z + fmaxf(t3 + bf2f(gg.w), 0.f) * w4.w;
#pragma unroll
    for (int off = 32; off > 0; off >>= 1) {
        accp += __shfl_down(accp, off, 64);
        accn += __shfl_down(accn, off, 64);
    }
    if (lane == 0) {
        float bb = fc2_b[0];
        out[e] = 1.0f / (1.0f + expf(-(accp + bb)));
        out[N_EDGES + e] = 1.0f / (1.0f + expf(-(accn + bb)));
    }
}

extern "C" void kernel_launch(void* const* d_in, const int* in_sizes, int n_in,
                              void* d_out, int out_size, void* d_ws, size_t ws_size,
                              hipStream_t stream) {
    const float* node_feat = (const float*)d_in[0];
    const int* src = (const int*)d_in[1];
    const int* dst = (const int*)d_in[2];
    const int* neg = (const int*)d_in[3];
    const float* W1 = (const float*)d_in[4];  const float* b1 = (const float*)d_in[5];
    const float* W2 = (const float*)d_in[6];  const float* b2 = (const float*)d_in[7];
    const float* W3 = (const float*)d_in[8];  const float* b3 = (const float*)d_in[9];
    const float* g1 = (const float*)d_in[10]; const float* be1 = (const float*)d_in[11];
    const float* g2 = (const float*)d_in[12]; const float* be2 = (const float*)d_in[13];
    const float* fc1_w = (const float*)d_in[14]; const float* fc1_b = (const float*)d_in[15];
    const float* fc2_w = (const float*)d_in[16]; const float* fc2_b = (const float*)d_in[17];
    float* out = (float*)d_out;

    const size_t NF = (size_t)N_NODES * CH;  // 25,600,000
    float* bufB = (float*)d_ws;              // fp32 aggregated / z (NF)
    bf16* Xbf = (bf16*)(bufB + NF);          // bf16 input activations (NF)
    bf16* XwBf = Xbf + NF;                   // bf16 GEMM output xw (NF)
    bf16* Ubf = XwBf + NF;                   // bf16 u (NF)
    bf16* Vbf = Ubf + NF;                    // bf16 v (NF)
    bf16* wt1 = Vbf + NF;                    // 65536 each
    bf16* wt2 = wt1 + 65536;
    bf16* wt3 = wt2 + 65536;
    bf16* wtu = wt3 + 65536;
    bf16* wtv = wtu + 65536;
    float* dinv = (float*)(wtv + 65536);
    float* bnsum = dinv + N_NODES;
    float* bnsumsq = bnsum + CH;
    float* scale = bnsumsq + CH;
    float* shift = scale + CH;
    int* ideg = (int*)(shift + CH);
    int* cursor = ideg + N_NODES;
    int* row_ptr = cursor + N_NODES;
    int* col = row_ptr + N_NODES + 1;
    int* bsum = col + N_EDGES;
    (void)ws_size;

    dim3 gemmGrid(2, (N_NODES + 127) / 128);  // 2 x 782
    int nodeBlocks = (N_NODES + 255) / 256;
    int edgeBlocks = (N_EDGES + 255) / 256;
    int aggBlocks = (N_NODES + 3) / 4;
    int v4Blocks = (int)(NF / 4 / 256);       // 25000
    int scoreBlocks = (N_EDGES + 3) / 4;

    // ---- CSR build + dinv ----
    k_zero_int<<<nodeBlocks, 256, 0, stream>>>(ideg, N_NODES);
    k_zero_int<<<nodeBlocks, 256, 0, stream>>>(cursor, N_NODES);
    k_count_deg<<<edgeBlocks, 256, 0, stream>>>(dst, ideg);
    k_dinv_from_deg<<<nodeBlocks, 256, 0, stream>>>(ideg, dinv);
    k_block_sums<<<nodeBlocks, 256, 0, stream>>>(ideg, bsum);
    k_scan_bsums<<<1, 512, 0, stream>>>(bsum, nodeBlocks);
    k_row_ptr<<<nodeBlocks, 256, 0, stream>>>(ideg, bsum, row_ptr);
    k_scatter<<<edgeBlocks, 256, 0, stream>>>(src, dst, row_ptr, cursor, col);

    // ---- weight transpose+cast (bf16 [N][K]) ----
    k_transpose_cast<<<256, 256, 0, stream>>>(W1, wt1, 0);
    k_transpose_cast<<<256, 256, 0, stream>>>(W2, wt2, 0);
    k_transpose_cast<<<256, 256, 0, stream>>>(W3, wt3, 0);
    k_transpose_cast<<<256, 256, 0, stream>>>(fc1_w, wtu, 0);
    k_transpose_cast<<<256, 256, 0, stream>>>(fc1_w, wtv, 256);

    // ---- layer 1 ----
    k_cast_bf16_v4<<<v4Blocks, 256, 0, stream>>>(node_feat, (unsigned short*)Xbf);
    k_gemm_mfma<bf16><<<gemmGrid, 256, 0, stream>>>(Xbf, wt1, XwBf, N_NODES);
    k_agg_csr<<<aggBlocks, 256, 0, stream>>>((unsigned short*)XwBf, dinv, row_ptr, col, b1, bufB);
    k_bn_zero<<<1, 256, 0, stream>>>(bnsum, bnsumsq);
    k_bn_stats<<<nodeBlocks, 256, 0, stream>>>(bufB, bnsum, bnsumsq);
    k_bn_finalize<<<1, 256, 0, stream>>>(bnsum, bnsumsq, g1, be1, scale, shift);
    k_bn_relu_cast_v4<<<v4Blocks, 256, 0, stream>>>(bufB, scale, shift, (unsigned short*)Xbf);

    // ---- layer 2 ----
    k_gemm_mfma<bf16><<<gemmGrid, 256, 0, stream>>>(Xbf, wt2, XwBf, N_NODES);
    k_agg_csr<<<aggBlocks, 256, 0, stream>>>((unsigned short*)XwBf, dinv, row_ptr, col, b2, bufB);
    k_bn_zero<<<1, 256, 0, stream>>>(bnsum, bnsumsq);
    k_bn_stats<<<nodeBlocks, 256, 0, stream>>>(bufB, bnsum, bnsumsq);
    k_bn_finalize<<<1, 256, 0, stream>>>(bnsum, bnsumsq, g2, be2, scale, shift);
    k_bn_relu_cast_v4<<<v4Blocks, 256, 0, stream>>>(bufB, scale, shift, (unsigned short*)Xbf);

    // ---- layer 3 ----
    k_gemm_mfma<bf16><<<gemmGrid, 256, 0, stream>>>(Xbf, wt3, XwBf, N_NODES);
    k_agg_csr<<<aggBlocks, 256, 0, stream>>>((unsigned short*)XwBf, dinv, row_ptr, col, b3, bufB);

    // ---- link predictor ----
    k_cast_bf16_v4<<<v4Blocks, 256, 0, stream>>>(bufB, (unsigned short*)Xbf);  // z -> bf16
    k_gemm_mfma<bf16><<<gemmGrid, 256, 0, stream>>>(Xbf, wtu, Ubf, N_NODES);
    k_gemm_mfma<bf16><<<gemmGrid, 256, 0, stream>>>(Xbf, wtv, Vbf, N_NODES);
    k_edge_score<<<scoreBlocks, 256, 0, stream>>>((unsigned short*)Ubf, (unsigned short*)Vbf,
                                                  src, dst, neg, fc1_b, fc2_w, fc2_b, out);
}